// Round 1
// baseline (773.429 us; speedup 1.0000x reference)
//
#include <hip/hip_runtime.h>
#include <math.h>

#define D 128
#define NG 128

// ---------------- fake-quant (per-tensor symmetric int4) ----------------
__global__ __launch_bounds__(256) void quant_kernel(
    const float* __restrict__ w0, const float* __restrict__ w1,
    const float* __restrict__ w2, const float* __restrict__ w3,
    const float* __restrict__ w4, const float* __restrict__ w5,
    float* __restrict__ qout) {
  const float* w;
  switch (blockIdx.x) {
    case 0: w = w0; break;
    case 1: w = w1; break;
    case 2: w = w2; break;
    case 3: w = w3; break;
    case 4: w = w4; break;
    default: w = w5; break;
  }
  float* q = qout + (size_t)blockIdx.x * (D * D);
  __shared__ float red[256];
  float m = 0.f;
  for (int i = threadIdx.x; i < D * D; i += 256) m = fmaxf(m, fabsf(w[i]));
  red[threadIdx.x] = m;
  __syncthreads();
  for (int s = 128; s > 0; s >>= 1) {
    if (threadIdx.x < s) red[threadIdx.x] = fmaxf(red[threadIdx.x], red[threadIdx.x + s]);
    __syncthreads();
  }
  float s = red[0] / 7.0f;
  for (int i = threadIdx.x; i < D * D; i += 256) {
    float r = rintf(w[i] / s);            // jnp.round == round-half-even == rintf
    r = fminf(fmaxf(r, -8.f), 7.f);
    q[i] = (s > 0.f) ? r * s : 0.f;
  }
}

// ---------------- CSR build ----------------
__global__ void count_deg(const int* __restrict__ dst, int* __restrict__ cnt, int E) {
  int e = blockIdx.x * blockDim.x + threadIdx.x;
  if (e < E) atomicAdd(&cnt[dst[e]], 1);
}

__global__ __launch_bounds__(1024) void scan_kernel(const int* __restrict__ cnt,
                                                    int* __restrict__ indptr, int n) {
  __shared__ int lds[1024];
  __shared__ int carry_s;
  if (threadIdx.x == 0) carry_s = 0;
  __syncthreads();
  for (int base = 0; base < n; base += 1024) {
    int i = base + threadIdx.x;
    int v = (i < n) ? cnt[i] : 0;
    lds[threadIdx.x] = v;
    __syncthreads();
    for (int off = 1; off < 1024; off <<= 1) {
      int t = (threadIdx.x >= off) ? lds[threadIdx.x - off] : 0;
      __syncthreads();
      lds[threadIdx.x] += t;
      __syncthreads();
    }
    int incl = lds[threadIdx.x];
    int carry = carry_s;
    if (i < n) indptr[i] = carry + incl - v;  // exclusive
    __syncthreads();
    if (threadIdx.x == 1023) carry_s = carry + lds[1023];
    __syncthreads();
  }
  if (threadIdx.x == 0) indptr[n] = carry_s;
}

__global__ void fill_csr(const int* __restrict__ dst, const int* __restrict__ src,
                         int* __restrict__ cursor, int* __restrict__ esrc, int E) {
  int e = blockIdx.x * blockDim.x + threadIdx.x;
  if (e >= E) return;
  int pos = atomicAdd(&cursor[dst[e]], 1);
  esrc[pos] = src[e];
}

// ---------------- GIN aggregation: out[n] = h[n] + sum_{e: dst==n} h[src[e]] ----------------
__global__ __launch_bounds__(256) void aggregate_kernel(
    const float* __restrict__ h, const int* __restrict__ indptr,
    const int* __restrict__ esrc, float* __restrict__ out, int n) {
  int node = blockIdx.x * blockDim.y + threadIdx.y;
  if (node >= n) return;
  int d = threadIdx.x;  // 0..31, float4 lanes
  const float4* hp = reinterpret_cast<const float4*>(h);
  float4 acc = hp[(size_t)node * 32 + d];
  int beg = indptr[node], end = indptr[node + 1];
  for (int e = beg; e < end; ++e) {
    int s = esrc[e];
    float4 v = hp[(size_t)s * 32 + d];
    acc.x += v.x; acc.y += v.y; acc.z += v.z; acc.w += v.w;
  }
  reinterpret_cast<float4*>(out)[(size_t)node * 32 + d] = acc;
}

// ---------------- f32 GEMM: C[M,128] = A[M,128] @ W[128,128]^T + bias (opt relu) ----------
__global__ __launch_bounds__(256) void gemm_kernel(
    const float* __restrict__ A, const float* __restrict__ W,
    const float* __restrict__ bias, float* __restrict__ C,
    int M, int relu) {
  __shared__ float As[64][128];
  __shared__ float Bs[64][128];
  const int tid = threadIdx.x;
  const int m0 = blockIdx.x * 64;
  const int n0 = blockIdx.y * 64;
  const int c4 = (tid & 31) * 4;  // col (float4 granule)
  const int r0 = tid >> 5;        // 0..7
  for (int rr = 0; rr < 64; rr += 8) {
    int row = rr + r0;
    int gm = m0 + row;
    float4 v = make_float4(0.f, 0.f, 0.f, 0.f);
    if (gm < M) v = *reinterpret_cast<const float4*>(A + (size_t)gm * D + c4);
    int cs = (c4 + 4 * row) & 127;  // rotation swizzle kills stride-128 bank conflicts
    *reinterpret_cast<float4*>(&As[row][cs]) = v;
    float4 wv = *reinterpret_cast<const float4*>(W + (size_t)(n0 + row) * D + c4);
    *reinterpret_cast<float4*>(&Bs[row][cs]) = wv;
  }
  __syncthreads();
  const int tx = tid & 15;
  const int ty = tid >> 4;
  float acc[4][4] = {};
  for (int k = 0; k < D; k += 4) {
    float4 a[4], b[4];
#pragma unroll
    for (int i = 0; i < 4; i++) {
      int row = ty + 16 * i;
      a[i] = *reinterpret_cast<const float4*>(&As[row][(k + 4 * row) & 127]);
    }
#pragma unroll
    for (int j = 0; j < 4; j++) {
      int row = tx + 16 * j;
      b[j] = *reinterpret_cast<const float4*>(&Bs[row][(k + 4 * row) & 127]);
    }
#pragma unroll
    for (int i = 0; i < 4; i++)
#pragma unroll
      for (int j = 0; j < 4; j++)
        acc[i][j] += a[i].x * b[j].x + a[i].y * b[j].y + a[i].z * b[j].z + a[i].w * b[j].w;
  }
#pragma unroll
  for (int i = 0; i < 4; i++) {
    int gm = m0 + ty + 16 * i;
    if (gm >= M) continue;
#pragma unroll
    for (int j = 0; j < 4; j++) {
      int gn = n0 + tx + 16 * j;
      float v = acc[i][j] + bias[gn];
      if (relu) v = fmaxf(v, 0.f);
      C[(size_t)gm * D + gn] = v;
    }
  }
}

// ---------------- graph mean pool (batch is sorted) ----------------
__global__ __launch_bounds__(128) void pool_kernel(const float* __restrict__ h,
                                                   const int* __restrict__ batch,
                                                   int n, float* __restrict__ out) {
  int g = blockIdx.x;
  __shared__ int sbeg, send;
  if (threadIdx.x == 0) {
    int lo = 0, hi = n;
    while (lo < hi) { int mid = (lo + hi) >> 1; if (batch[mid] < g) lo = mid + 1; else hi = mid; }
    sbeg = lo;
    hi = n;
    while (lo < hi) { int mid = (lo + hi) >> 1; if (batch[mid] < g + 1) lo = mid + 1; else hi = mid; }
    send = lo;
  }
  __syncthreads();
  int beg = sbeg, end = send;
  int d = threadIdx.x;
  float acc = 0.f;
  for (int i = beg; i < end; ++i) acc += h[(size_t)i * D + d];
  float cnt = (float)(end - beg);
  out[(size_t)g * D + d] = acc / fmaxf(cnt, 1.0f);
}

extern "C" void kernel_launch(void* const* d_in, const int* in_sizes, int n_in,
                              void* d_out, int out_size, void* d_ws, size_t ws_size,
                              hipStream_t stream) {
  const float* x = (const float*)d_in[0];
  const int* ei = (const int*)d_in[1];
  const int* batch = (const int*)d_in[2];
  const float* w[6] = {(const float*)d_in[3], (const float*)d_in[5],
                       (const float*)d_in[7], (const float*)d_in[9],
                       (const float*)d_in[11], (const float*)d_in[13]};
  const float* b[6] = {(const float*)d_in[4], (const float*)d_in[6],
                       (const float*)d_in[8], (const float*)d_in[10],
                       (const float*)d_in[12], (const float*)d_in[14]};
  const int N = in_sizes[0] / D;
  const int E = in_sizes[1] / 2;
  const int* src = ei;
  const int* dst = ei + E;

  // workspace carve-up (256B aligned)
  char* ws = (char*)d_ws;
  size_t off = 0;
  auto carve = [&](size_t bytes) -> char* {
    char* p = ws + off;
    off = (off + bytes + 255) & ~(size_t)255;
    return p;
  };
  float* hA = (float*)carve((size_t)N * D * 4);
  float* hB = (float*)carve((size_t)N * D * 4);
  float* qw = (float*)carve(6 * D * D * 4);
  int* cnt = (int*)carve((size_t)N * 4);
  int* indptr = (int*)carve((size_t)(N + 1) * 4);
  int* cursor = (int*)carve((size_t)(N + 1) * 4);
  int* esrc = (int*)carve((size_t)E * 4);
  if (off > ws_size) return;  // fail loudly via validation rather than corrupt

  // 1) quantize weights
  quant_kernel<<<6, 256, 0, stream>>>(w[0], w[1], w[2], w[3], w[4], w[5], qw);

  // 2) CSR build
  hipMemsetAsync(cnt, 0, (size_t)N * 4, stream);
  count_deg<<<(E + 255) / 256, 256, 0, stream>>>(dst, cnt, E);
  scan_kernel<<<1, 1024, 0, stream>>>(cnt, indptr, N);
  hipMemcpyAsync(cursor, indptr, (size_t)N * 4, hipMemcpyDeviceToDevice, stream);
  fill_csr<<<(E + 255) / 256, 256, 0, stream>>>(dst, src, cursor, esrc, E);

  // 3) 3 GIN layers, ping-pong hA/hB
  const float* cur = x;
  dim3 aggBlock(32, 8);
  dim3 gemmGrid((N + 63) / 64, 2);
  for (int l = 0; l < 3; ++l) {
    float* t0 = (cur == (const float*)hA) ? hB : hA;  // agg out
    float* t1 = (t0 == hA) ? hB : hA;                 // gemm1 out
    aggregate_kernel<<<(N + 7) / 8, aggBlock, 0, stream>>>(cur, indptr, esrc, t0, N);
    gemm_kernel<<<gemmGrid, 256, 0, stream>>>(t0, qw + (size_t)(2 * l) * D * D, b[2 * l], t1, N, 1);
    gemm_kernel<<<gemmGrid, 256, 0, stream>>>(t1, qw + (size_t)(2 * l + 1) * D * D, b[2 * l + 1], t0, N,
                                              (l < 2) ? 1 : 0);
    cur = t0;
  }

  // 4) mean pool
  pool_kernel<<<NG, D, 0, stream>>>(cur, batch, N, (float*)d_out);
}

// Round 2
// 287.041 us; speedup vs baseline: 2.6945x; 2.6945x over previous
//
#include <hip/hip_runtime.h>
#include <math.h>

#define D 128
#define NG 128
#define SLOTS 64

typedef __attribute__((ext_vector_type(8))) unsigned short u16x8;
typedef __attribute__((ext_vector_type(8))) short bf16x8;
typedef __attribute__((ext_vector_type(4))) float f32x4;

__device__ __forceinline__ float bf2f(unsigned short u) {
  return __uint_as_float(((unsigned int)u) << 16);
}
__device__ __forceinline__ unsigned short f2bf(float f) {
  unsigned int u = __float_as_uint(f);
  u += 0x7FFFu + ((u >> 16) & 1u);  // round-to-nearest-even
  return (unsigned short)(u >> 16);
}

// ---------------- fake-quant (per-tensor symmetric int4) -> bf16 ----------------
__global__ __launch_bounds__(256) void quant_kernel(
    const float* __restrict__ w0, const float* __restrict__ w1,
    const float* __restrict__ w2, const float* __restrict__ w3,
    const float* __restrict__ w4, const float* __restrict__ w5,
    unsigned short* __restrict__ qout) {
  const float* w;
  switch (blockIdx.x) {
    case 0: w = w0; break;
    case 1: w = w1; break;
    case 2: w = w2; break;
    case 3: w = w3; break;
    case 4: w = w4; break;
    default: w = w5; break;
  }
  unsigned short* q = qout + (size_t)blockIdx.x * (D * D);
  __shared__ float red[256];
  float m = 0.f;
  for (int i = threadIdx.x; i < D * D; i += 256) m = fmaxf(m, fabsf(w[i]));
  red[threadIdx.x] = m;
  __syncthreads();
  for (int s = 128; s > 0; s >>= 1) {
    if (threadIdx.x < s) red[threadIdx.x] = fmaxf(red[threadIdx.x], red[threadIdx.x + s]);
    __syncthreads();
  }
  float s = red[0] / 7.0f;
  for (int i = threadIdx.x; i < D * D; i += 256) {
    float r = rintf(w[i] / s);  // jnp.round == round-half-even
    r = fminf(fmaxf(r, -8.f), 7.f);
    q[i] = f2bf((s > 0.f) ? r * s : 0.f);
  }
}

// ---------------- x (f32) -> bf16 ----------------
__global__ __launch_bounds__(256) void convert_kernel(const float* __restrict__ x,
                                                      unsigned short* __restrict__ o, int n8) {
  int i = blockIdx.x * 256 + threadIdx.x;
  if (i >= n8) return;
  const float4* xp = reinterpret_cast<const float4*>(x) + (size_t)i * 2;
  float4 a = xp[0], b = xp[1];
  u16x8 v;
  v[0] = f2bf(a.x); v[1] = f2bf(a.y); v[2] = f2bf(a.z); v[3] = f2bf(a.w);
  v[4] = f2bf(b.x); v[5] = f2bf(b.y); v[6] = f2bf(b.z); v[7] = f2bf(b.w);
  *(reinterpret_cast<u16x8*>(o) + i) = v;
}

// ---------------- slot-bucket build (one atomic pass, no scan) ----------------
__global__ void build_slots(const int* __restrict__ dst, const int* __restrict__ src,
                            int* __restrict__ cnt, int* __restrict__ esrc, int E) {
  int e = blockIdx.x * blockDim.x + threadIdx.x;
  if (e >= E) return;
  int d = dst[e];
  int slot = atomicAdd(&cnt[d], 1);
  if (slot < SLOTS) esrc[(size_t)d * SLOTS + slot] = src[e];
}

// ---------------- GIN aggregation (bf16 in/out, f32 accumulate) ----------------
__global__ __launch_bounds__(256) void aggregate_kernel(
    const unsigned short* __restrict__ h, const int* __restrict__ cnt,
    const int* __restrict__ esrc, unsigned short* __restrict__ out, int n) {
  int node = blockIdx.x * 16 + threadIdx.y;
  if (node >= n) return;
  int x = threadIdx.x;  // 0..15, 16B granule of the 256B row
  const u16x8* hp = reinterpret_cast<const u16x8*>(h);
  u16x8 v = hp[(size_t)node * 16 + x];
  float acc[8];
#pragma unroll
  for (int i = 0; i < 8; i++) acc[i] = bf2f(v[i]);
  int c = cnt[node];
  if (c > SLOTS) c = SLOTS;
  const int* base = esrc + (size_t)node * SLOTS;
  for (int e = 0; e < c; ++e) {
    int s = base[e];
    u16x8 w = hp[(size_t)s * 16 + x];
#pragma unroll
    for (int i = 0; i < 8; i++) acc[i] += bf2f(w[i]);
  }
  u16x8 r;
#pragma unroll
  for (int i = 0; i < 8; i++) r[i] = f2bf(acc[i]);
  reinterpret_cast<u16x8*>(out)[(size_t)node * 16 + x] = r;
}

// ---------------- bf16 MFMA GEMM: C[M,128] = A[M,128] @ W[128,128]^T + bias ----------------
// A row-major bf16; W row-major bf16 (so B[k][n] = W[n][k] -> both operands are
// plain 16B row loads per the 16x16x32 fragment layout).
__global__ __launch_bounds__(256) void gemm_mfma(
    const unsigned short* __restrict__ A, const unsigned short* __restrict__ Wq,
    const float* __restrict__ bias, unsigned short* __restrict__ C, int M, int relu) {
  __shared__ unsigned short Ws[128 * 128];  // 32 KB, XOR-swizzled granules
  const int tid = threadIdx.x;
  // stage W: 2048 granules of 8 elems; granule g of row -> slot g^(row&15)
#pragma unroll
  for (int i = 0; i < 8; i++) {
    int gid = tid + 256 * i;
    int row = gid >> 4;
    int g = gid & 15;
    u16x8 v = *reinterpret_cast<const u16x8*>(Wq + (size_t)row * D + g * 8);
    int gs = g ^ (row & 15);
    *reinterpret_cast<u16x8*>(&Ws[row * D + gs * 8]) = v;
  }
  __syncthreads();

  const int lane = tid & 63;
  const int wave = tid >> 6;
  const int m0 = blockIdx.x * 64 + wave * 16;
  const int mrow = m0 + (lane & 15);
  const unsigned short* arow = A + (size_t)mrow * D + (lane >> 4) * 8;

  f32x4 acc[8] = {};
#pragma unroll
  for (int ks = 0; ks < 4; ks++) {
    bf16x8 a = *reinterpret_cast<const bf16x8*>(arow + ks * 32);
#pragma unroll
    for (int j = 0; j < 8; j++) {
      int row = j * 16 + (lane & 15);
      int g = ks * 4 + (lane >> 4);
      int gs = g ^ (row & 15);
      bf16x8 b = *reinterpret_cast<const bf16x8*>(&Ws[row * D + gs * 8]);
      acc[j] = __builtin_amdgcn_mfma_f32_16x16x32_bf16(a, b, acc[j], 0, 0, 0);
    }
  }
  // C/D layout: col = lane&15, row = (lane>>4)*4 + reg
#pragma unroll
  for (int j = 0; j < 8; j++) {
    int col = j * 16 + (lane & 15);
    float bb = bias[col];
#pragma unroll
    for (int r = 0; r < 4; r++) {
      int row = m0 + (lane >> 4) * 4 + r;
      if (row < M) {
        float v = acc[j][r] + bb;
        if (relu) v = fmaxf(v, 0.f);
        C[(size_t)row * D + col] = f2bf(v);
      }
    }
  }
}

// ---------------- graph mean pool (bf16 in, f32 out; batch sorted) ----------------
__global__ __launch_bounds__(256) void pool_kernel(const unsigned short* __restrict__ h,
                                                   const int* __restrict__ batch, int n,
                                                   float* __restrict__ out) {
  int g = blockIdx.x;
  __shared__ int sbeg, send;
  if (threadIdx.x == 0) {
    int lo = 0, hi = n;
    while (lo < hi) { int mid = (lo + hi) >> 1; if (batch[mid] < g) lo = mid + 1; else hi = mid; }
    sbeg = lo;
    hi = n;
    while (lo < hi) { int mid = (lo + hi) >> 1; if (batch[mid] < g + 1) lo = mid + 1; else hi = mid; }
    send = lo;
  }
  __syncthreads();
  int beg = sbeg, end = send;
  int x = threadIdx.x & 15;   // 16B granule
  int ty = threadIdx.x >> 4;  // 0..15 row group
  const u16x8* hp = reinterpret_cast<const u16x8*>(h);
  float acc[8] = {};
  for (int i = beg + ty; i < end; i += 16) {
    u16x8 v = hp[(size_t)i * 16 + x];
#pragma unroll
    for (int k = 0; k < 8; k++) acc[k] += bf2f(v[k]);
  }
  __shared__ float red[16][16][8];
#pragma unroll
  for (int k = 0; k < 8; k++) red[ty][x][k] = acc[k];
  __syncthreads();
  for (int s = 8; s > 0; s >>= 1) {
    if (ty < s) {
#pragma unroll
      for (int k = 0; k < 8; k++) red[ty][x][k] += red[ty + s][x][k];
    }
    __syncthreads();
  }
  if (ty == 0) {
    float inv = 1.0f / fmaxf((float)(end - beg), 1.0f);
#pragma unroll
    for (int k = 0; k < 8; k++) out[(size_t)g * D + x * 8 + k] = red[0][x][k] * inv;
  }
}

extern "C" void kernel_launch(void* const* d_in, const int* in_sizes, int n_in,
                              void* d_out, int out_size, void* d_ws, size_t ws_size,
                              hipStream_t stream) {
  const float* x = (const float*)d_in[0];
  const int* ei = (const int*)d_in[1];
  const int* batch = (const int*)d_in[2];
  const float* w[6] = {(const float*)d_in[3], (const float*)d_in[5],
                       (const float*)d_in[7], (const float*)d_in[9],
                       (const float*)d_in[11], (const float*)d_in[13]};
  const float* b[6] = {(const float*)d_in[4], (const float*)d_in[6],
                       (const float*)d_in[8], (const float*)d_in[10],
                       (const float*)d_in[12], (const float*)d_in[14]};
  const int N = in_sizes[0] / D;
  const int E = in_sizes[1] / 2;
  const int* src = ei;
  const int* dst = ei + E;

  char* ws = (char*)d_ws;
  size_t off = 0;
  auto carve = [&](size_t bytes) -> char* {
    char* p = ws + off;
    off = (off + bytes + 255) & ~(size_t)255;
    return p;
  };
  unsigned short* hA = (unsigned short*)carve((size_t)N * D * 2);
  unsigned short* hB = (unsigned short*)carve((size_t)N * D * 2);
  unsigned short* qw = (unsigned short*)carve(6 * D * D * 2);
  int* cnt = (int*)carve((size_t)N * 4);
  int* esrc = (int*)carve((size_t)N * SLOTS * 4);
  if (off > ws_size) return;

  // 1) quantize weights -> bf16
  quant_kernel<<<6, 256, 0, stream>>>(w[0], w[1], w[2], w[3], w[4], w[5], qw);

  // 2) slot buckets (single atomic pass)
  hipMemsetAsync(cnt, 0, (size_t)N * 4, stream);
  build_slots<<<(E + 255) / 256, 256, 0, stream>>>(dst, src, cnt, esrc, E);

  // 3) x -> bf16
  convert_kernel<<<(N * D / 8 + 255) / 256, 256, 0, stream>>>(x, hA, N * D / 8);

  // 4) 3 GIN layers (ping-pong hA/hB)
  unsigned short* cur = hA;
  unsigned short* oth = hB;
  dim3 aggBlock(16, 16);
  int gemmGrid = (N + 63) / 64;
  for (int l = 0; l < 3; ++l) {
    aggregate_kernel<<<(N + 15) / 16, aggBlock, 0, stream>>>(cur, cnt, esrc, oth, N);
    gemm_mfma<<<gemmGrid, 256, 0, stream>>>(oth, qw + (size_t)(2 * l) * D * D, b[2 * l], cur, N, 1);
    gemm_mfma<<<gemmGrid, 256, 0, stream>>>(cur, qw + (size_t)(2 * l + 1) * D * D, b[2 * l + 1], oth,
                                            N, (l < 2) ? 1 : 0);
    unsigned short* t = cur; cur = oth; oth = t;
  }

  // 5) mean pool -> f32 out
  pool_kernel<<<NG, 256, 0, stream>>>(cur, batch, N, (float*)d_out);
}